// Round 23
// baseline (77.359 us; speedup 1.0000x reference)
//
#include <hip/hip_runtime.h>
#include <hip/hip_bf16.h>

#define BB 32
#define IDF 64
#define CDF 256
#define SSZ 1024
#define NH 8
#define LL 256
#define KHC 2048   // NH*CDF

typedef __attribute__((ext_vector_type(8))) _Float16 half8v;   // 8 fp16
typedef __attribute__((ext_vector_type(4))) float f32x4;       // MFMA acc

// async global->LDS, 16B per lane, LDS dest = wave-uniform base + lane*16
#define GLDS16(g, l) __builtin_amdgcn_global_load_lds(                        \
    (const __attribute__((address_space(1))) void*)(g),                       \
    (__attribute__((address_space(3))) void*)(l), 16, 0, 0)

// 3-deep pipeline phase entry (T3+T4): wait only for the CURRENT buffer's
// DMA, leaving the next TWO stages in flight. Never vmcnt(0) mid-loop.
#define WAIT_ENTER3(NFULL, NHALF)                                             \
  { if (ks < NSTEP - 2)                                                       \
      asm volatile("s_waitcnt vmcnt(" #NFULL ")" ::: "memory");               \
    else if (ks == NSTEP - 2)                                                 \
      asm volatile("s_waitcnt vmcnt(" #NHALF ")" ::: "memory");               \
    else                                                                      \
      asm volatile("s_waitcnt vmcnt(0)" ::: "memory");                        \
    __builtin_amdgcn_s_barrier();                                             \
    __builtin_amdgcn_sched_barrier(0); }
// phase-1 variant: PER-WAVE vmcnt constants (waves 0-3 issue 3 insts/stage,
// waves 4-7 issue 2) — no dup instructions needed for vmcnt uniformity.
#define WAIT_P1()                                                             \
  { if (ks < NSTEP - 2) {                                                     \
      if (wave < 4) asm volatile("s_waitcnt vmcnt(6)" ::: "memory");          \
      else          asm volatile("s_waitcnt vmcnt(4)" ::: "memory");          \
    } else if (ks == NSTEP - 2) {                                             \
      if (wave < 4) asm volatile("s_waitcnt vmcnt(3)" ::: "memory");          \
      else          asm volatile("s_waitcnt vmcnt(2)" ::: "memory");          \
    } else asm volatile("s_waitcnt vmcnt(0)" ::: "memory");                   \
    __builtin_amdgcn_s_barrier();                                             \
    __builtin_amdgcn_sched_barrier(0); }
#define BAR_EXIT()                                                            \
  { __builtin_amdgcn_sched_barrier(0);                                        \
    __builtin_amdgcn_s_barrier();                                             \
    __builtin_amdgcn_sched_barrier(0); }
// LDS-only barrier: drains ds ops but leaves global_load_lds (vmcnt) in
// flight — lets phase-3 prefetch ride through the softmax.
#define LDS_BAR()                                                             \
  { asm volatile("s_waitcnt lgkmcnt(0)" ::: "memory");                        \
    __builtin_amdgcn_s_barrier();                                             \
    __builtin_amdgcn_sched_barrier(0); }

__device__ inline unsigned short f2h(float x) {
  _Float16 h = (_Float16)x;
  return *reinterpret_cast<unsigned short*>(&h);
}
__device__ inline float h2f(unsigned short u) {
  _Float16 h = *reinterpret_cast<_Float16*>(&u);
  return (float)h;
}

// ---------------------------------------------------------------------------
// Fused prep (grid 5120):
//  blocks    0..2047: wc -> wc16 elementwise cast
//  blocks 2048..2559: W tile -> Wt16 [h][c][o] transpose AND W16 (fused emit)
//  blocks 2560..3071: ctx tile -> cT16 [b][l][c] transpose AND ctx16
//  blocks 3072..5119: zero ctx_out region of d_out (k4 accumulates atomically)
// ---------------------------------------------------------------------------
__global__ __launch_bounds__(256) void k_prep(const float* __restrict__ wc,
                                              const float* __restrict__ W,
                                              const float* __restrict__ ctx,
                                              unsigned short* __restrict__ wc16,
                                              unsigned short* __restrict__ W16,
                                              unsigned short* __restrict__ ctx16,
                                              unsigned short* __restrict__ Wt16,
                                              unsigned short* __restrict__ cT16,
                                              float* __restrict__ outz) {
  __shared__ float Tt[64][65];
  int blk0 = blockIdx.x;
  int t = threadIdx.x;
  if (blk0 < 2048) {                       // wc cast
    int idx = (blk0 * 256 + t) * 4;
    float4 v = *reinterpret_cast<const float4*>(&wc[idx]);
    __align__(8) unsigned short h[4] = {f2h(v.x), f2h(v.y), f2h(v.z), f2h(v.w)};
    *reinterpret_cast<int2*>(&wc16[idx]) = *reinterpret_cast<int2*>(h);
  } else if (blk0 < 2560) {                // W -> Wt16 (+W16)
    int blk = blk0 - 2048;
    int h = blk >> 6, ot = (blk >> 2) & 15, cq = blk & 3;
    int og = ot * 64, cg = cq * 64;
    int o_l = t >> 4, c4 = (t & 15) * 4;
#pragma unroll
    for (int p = 0; p < 4; ++p) {
      int o = o_l + 16 * p;
      size_t gidx = ((size_t)h * SSZ + og + o) * CDF + cg + c4;
      float4 v = *reinterpret_cast<const float4*>(&W[gidx]);
      __align__(8) unsigned short hv[4] = {f2h(v.x), f2h(v.y), f2h(v.z), f2h(v.w)};
      *reinterpret_cast<int2*>(&W16[gidx]) = *reinterpret_cast<int2*>(hv);
      Tt[c4 + 0][o] = v.x; Tt[c4 + 1][o] = v.y;
      Tt[c4 + 2][o] = v.z; Tt[c4 + 3][o] = v.w;
    }
    __syncthreads();
    int c_l = t >> 2;
#pragma unroll
    for (int p = 0; p < 4; ++p) {
      int o0 = ((t & 3) + 4 * p) * 4;
      __align__(8) unsigned short hv[4];
#pragma unroll
      for (int j = 0; j < 4; ++j) hv[j] = f2h(Tt[c_l][o0 + j]);
      size_t base = ((size_t)h * CDF + cg + c_l) * SSZ + og + o0;
      *reinterpret_cast<int2*>(&Wt16[base]) = *reinterpret_cast<int2*>(hv);
    }
  } else if (blk0 < 3072) {                // ctx -> cT16 (+ctx16)
    int blk = blk0 - 2560;
    int b = blk >> 4, cq = (blk >> 2) & 3, lt = blk & 3;
    int cg = cq * 64, lg = lt * 64;
    int c_l = t >> 4, l4 = (t & 15) * 4;
#pragma unroll
    for (int p = 0; p < 4; ++p) {
      int c = c_l + 16 * p;
      size_t gidx = ((size_t)b * CDF + cg + c) * LL + lg + l4;
      float4 v = *reinterpret_cast<const float4*>(&ctx[gidx]);
      __align__(8) unsigned short hv[4] = {f2h(v.x), f2h(v.y), f2h(v.z), f2h(v.w)};
      *reinterpret_cast<int2*>(&ctx16[gidx]) = *reinterpret_cast<int2*>(hv);
      Tt[l4 + 0][c] = v.x; Tt[l4 + 1][c] = v.y;
      Tt[l4 + 2][c] = v.z; Tt[l4 + 3][c] = v.w;
    }
    __syncthreads();
    int l_l = t >> 2;
#pragma unroll
    for (int p = 0; p < 4; ++p) {
      int c0 = ((t & 3) + 4 * p) * 4;
      __align__(8) unsigned short hv[4];
#pragma unroll
      for (int j = 0; j < 4; ++j) hv[j] = f2h(Tt[l_l][c0 + j]);
      size_t base = ((size_t)b * LL + lg + l_l) * CDF + cg + c0;
      *reinterpret_cast<int2*>(&cT16[base]) = *reinterpret_cast<int2*>(hv);
    }
  } else {                                 // zero ctx_out (2M floats)
    int idx = ((blk0 - 3072) * 256 + t) * 4;
    *reinterpret_cast<float4*>(&outz[idx]) = make_float4(0.f, 0.f, 0.f, 0.f);
  }
}

// ---------------------------------------------------------------------------
// k123: fused K1+K2+K3, block = (b,h), 512 thr = 8 waves = 2 groups by
// row-half. Phase 1 stages Wt[h] once; phases 2/3 stage cT[b]/ctx[b] once.
// Phase-1 dup-A removed (per-wave vmcnt): 20 insts/step.
// LDS: 3 x 20KB staging + 32KB M/P_lds = 92 KB.
// ---------------------------------------------------------------------------
#define BUFS 10240   // shorts per staging buffer (20 KB): A [0,2048) B [2048,10240)

// phase-1 stage, 20 insts: waves 0-3 do {1 A, 2 B}; waves 4-7 do {2 B}.
__device__ __forceinline__ void st_p1(short* dst, const short* gA, const short* gB,
                                      int wave, int lane, int k0) {
  if (wave < 4) {                          // A rows 0..63
    int r = wave * 16 + (lane >> 2);
    int gc = (lane & 3) ^ ((r >> 1) & 3);
    GLDS16(gA + (size_t)r * SSZ + k0 + gc * 8, dst + wave * 512);
  }
#pragma unroll
  for (int j = 0; j < 2; ++j) {            // B rows 0..255
    int bi = wave * 2 + j;                 // 0..15
    int brow = bi * 16 + (lane >> 2);
    int gc = (lane & 3) ^ ((brow >> 1) & 3);
    GLDS16(gB + (size_t)brow * SSZ + k0 + gc * 8, dst + 2048 + bi * 512);
  }
}
// phase-2/3 stage, 16 insts (2/wave): shared B panel 256 rows @ [0,8192).
__device__ __forceinline__ void st_p23(short* dst, const short* gB, int ld,
                                       int wave, int lane, int k0) {
#pragma unroll
  for (int j = 0; j < 2; ++j) {
    int inst = wave * 2 + j;               // 0..15
    int brow = inst * 16 + (lane >> 2);    // 0..255
    int gc = (lane & 3) ^ ((brow >> 1) & 3);
    GLDS16(gB + (size_t)brow * ld + k0 + gc * 8, dst + inst * 512);
  }
}

__global__ __launch_bounds__(512) void k123(const unsigned short* __restrict__ wc16,
                                            const unsigned short* __restrict__ Wt16,
                                            const unsigned short* __restrict__ cT16,
                                            const unsigned short* __restrict__ ctx16,
                                            unsigned short* __restrict__ P16,
                                            unsigned short* __restrict__ N216) {
  __shared__ __align__(16) short S[3 * BUFS + 16384];   // 92 KB
  short* P_lds = &S[3 * BUFS];                           // 64 x 256 fp16

  int blk = blockIdx.x;                    // = bh
  int b = blk >> 3, h = blk & 7;
  int t = threadIdx.x;
  int lane = t & 63, wave = t >> 6;             // 0..7
  int g = wave >> 2, w4 = wave & 3;             // row-half group, wave-in-group
  int ln15 = lane & 15, kh = lane >> 4;
  int rowq = (lane >> 4) * 4;

  const short* gA = (const short*)wc16 + (size_t)b * IDF * SSZ;
  const short* gB = (const short*)Wt16 + (size_t)h * CDF * SSZ;
  const short* gT = (const short*)cT16 + (size_t)b * LL * CDF;
  const short* gC = (const short*)ctx16 + (size_t)b * CDF * LL;

  // A frag offsets: group g's rows = g*32 + r*16 + ln15 (global 0..63)
  int offA[2], rowM[2], rmask[2];
#pragma unroll
  for (int r = 0; r < 2; ++r) {
    int row = g * 32 + r * 16 + ln15;          // 0..63
    offA[r] = row * 32 + ((kh ^ ((row >> 1) & 3)) * 8);
    rowM[r] = row * 256;
    rmask[r] = row & 7;
  }
  // B frag offsets: phase 1 (Wt @2048) and phases 2/3 (shared panel @0)
  int offB1[4], offB2[4];
#pragma unroll
  for (int c = 0; c < 4; ++c) {
    int row = w4 * 64 + c * 16 + ln15;         // 0..255
    int swz = ((kh ^ ((row >> 1) & 3)) * 8);
    offB1[c] = 2048 + row * 32 + swz;
    offB2[c] = row * 32 + swz;
  }

  f32x4 acc[2][4] = {};

  // ===== Phase 1: M = wc x Wt^T, K=1024 =====
  st_p1(&S[0],        gA, gB, wave, lane, 0);
  st_p1(&S[BUFS],     gA, gB, wave, lane, 32);
  st_p1(&S[2 * BUFS], gA, gB, wave, lane, 64);
  int cur = 0;
  {
    const int NSTEP = 32;
#pragma unroll 1
    for (int ks = 0; ks < NSTEP; ++ks) {
      short* Sc = &S[cur * BUFS];
      WAIT_P1()
      half8v fa[2], fb[4];
#pragma unroll
      for (int r = 0; r < 2; ++r)
        fa[r] = *reinterpret_cast<const half8v*>(&Sc[offA[r]]);
#pragma unroll
      for (int c = 0; c < 4; ++c)
        fb[c] = *reinterpret_cast<const half8v*>(&Sc[offB1[c]]);
      __builtin_amdgcn_s_setprio(1);
#pragma unroll
      for (int r = 0; r < 2; ++r)
#pragma unroll
        for (int c = 0; c < 4; ++c)
          acc[r][c] = __builtin_amdgcn_mfma_f32_16x16x32_f16(fa[r], fb[c], acc[r][c], 0, 0, 0);
      __builtin_amdgcn_s_setprio(0);
      BAR_EXIT()
      if (ks + 3 < NSTEP)
        st_p1(Sc, gA, gB, wave, lane, (ks + 3) * 32);
      cur = (cur == 2) ? 0 : cur + 1;
    }
  }
  // M -> P_lds (fp16, chunk-XOR(row&7))
#pragma unroll
  for (int r = 0; r < 2; ++r)
#pragma unroll
    for (int c = 0; c < 4; ++c)
#pragma unroll
      for (int reg = 0; reg < 4; ++reg) {
        int row = g * 32 + r * 16 + rowq + reg;   // 0..63
        int col = w4 * 64 + c * 16 + ln15;        // 0..255
        P_lds[row * 256 + ((((col >> 3) ^ (row & 7)) << 3) + (col & 7))] =
            (short)f2h(acc[r][c][reg]);
      }
  LDS_BAR()

  // ===== Phase 2: logits = M_lds x cT[b]^T, K=256 (shared B) =====
#pragma unroll
  for (int r = 0; r < 2; ++r)
#pragma unroll
    for (int c = 0; c < 4; ++c) acc[r][c] = (f32x4){0.f, 0.f, 0.f, 0.f};
  st_p23(&S[0],        gT, CDF, wave, lane, 0);
  st_p23(&S[BUFS],     gT, CDF, wave, lane, 32);
  st_p23(&S[2 * BUFS], gT, CDF, wave, lane, 64);
  cur = 0;
  {
    const int NSTEP = 8;
#pragma unroll 1
    for (int ks = 0; ks < NSTEP; ++ks) {
      short* Sc = &S[cur * BUFS];
      WAIT_ENTER3(4, 2)
      half8v fa[2], fb[4];
#pragma unroll
      for (int r = 0; r < 2; ++r) {
        int ck = ((ks * 4 + kh) ^ rmask[r]) << 3;
        fa[r] = *reinterpret_cast<const half8v*>(&P_lds[rowM[r] + ck]);
      }
#pragma unroll
      for (int c = 0; c < 4; ++c)
        fb[c] = *reinterpret_cast<const half8v*>(&Sc[offB2[c]]);
      __builtin_amdgcn_s_setprio(1);
#pragma unroll
      for (int r = 0; r < 2; ++r)
#pragma unroll
        for (int c = 0; c < 4; ++c)
          acc[r][c] = __builtin_amdgcn_mfma_f32_16x16x32_f16(fa[r], fb[c], acc[r][c], 0, 0, 0);
      __builtin_amdgcn_s_setprio(0);
      BAR_EXIT()
      if (ks + 3 < NSTEP)
        st_p23(Sc, gT, CDF, wave, lane, (ks + 3) * 32);
      cur = (cur == 2) ? 0 : cur + 1;
    }
  }

  // Prefetch phase-3 B (ctx16) BEFORE softmax; stays in flight (LDS_BAR only).
  st_p23(&S[0],        gC, LL, wave, lane, 0);
  st_p23(&S[BUFS],     gC, LL, wave, lane, 32);
  st_p23(&S[2 * BUFS], gC, LL, wave, lane, 64);

  // ===== Softmax over l (cols). pm overlays first 1 KB of P_lds (M dead). =====
  float* pm = reinterpret_cast<float*>(P_lds);   // 64 rows x 4 floats
  float gmax[2][4], ginv[2][4];
#pragma unroll
  for (int r = 0; r < 2; ++r)
#pragma unroll
    for (int reg = 0; reg < 4; ++reg) {
      float m = fmaxf(fmaxf(acc[r][0][reg], acc[r][1][reg]),
                      fmaxf(acc[r][2][reg], acc[r][3][reg]));
#pragma unroll
      for (int msk = 8; msk >= 1; msk >>= 1) m = fmaxf(m, __shfl_xor(m, msk, 64));
      if (ln15 == 0) pm[(g * 32 + r * 16 + rowq + reg) * 4 + w4] = m;
    }
  LDS_BAR()
#pragma unroll
  for (int r = 0; r < 2; ++r)
#pragma unroll
    for (int reg = 0; reg < 4; ++reg) {
      int row = g * 32 + r * 16 + rowq + reg;
      float4 p0 = *reinterpret_cast<const float4*>(&pm[row * 4]);
      gmax[r][reg] = fmaxf(fmaxf(p0.x, p0.y), fmaxf(p0.z, p0.w));
    }
  LDS_BAR()
#pragma unroll
  for (int r = 0; r < 2; ++r)
#pragma unroll
    for (int reg = 0; reg < 4; ++reg) {
      float s = 0.f;
#pragma unroll
      for (int c = 0; c < 4; ++c) {
        acc[r][c][reg] = __expf(acc[r][c][reg] - gmax[r][reg]);
        s += acc[r][c][reg];
      }
#pragma unroll
      for (int msk = 8; msk >= 1; msk >>= 1) s += __shfl_xor(s, msk, 64);
      if (ln15 == 0) pm[(g * 32 + r * 16 + rowq + reg) * 4 + w4] = s;
    }
  LDS_BAR()
#pragma unroll
  for (int r = 0; r < 2; ++r)
#pragma unroll
    for (int reg = 0; reg < 4; ++reg) {
      int row = g * 32 + r * 16 + rowq + reg;
      float4 p0 = *reinterpret_cast<const float4*>(&pm[row * 4]);
      ginv[r][reg] = 1.f / (p0.x + p0.y + p0.z + p0.w);
    }
  LDS_BAR()   // pm fully consumed before P overwrites the region

  // P -> global (for transpose blocks) and -> P_lds (phase-3 A operand)
  size_t pbase = (size_t)blk * IDF * LL;
#pragma unroll
  for (int r = 0; r < 2; ++r)
#pragma unroll
    for (int c = 0; c < 4; ++c)
#pragma unroll
      for (int reg = 0; reg < 4; ++reg) {
        float p = acc[r][c][reg] * ginv[r][reg];
        int row = g * 32 + r * 16 + rowq + reg;
        int col = w4 * 64 + c * 16 + ln15;
        unsigned short ph = f2h(p);
        P16[pbase + (size_t)row * LL + col] = ph;
        P_lds[row * 256 + ((((col >> 3) ^ (row & 7)) << 3) + (col & 7))] = (short)ph;
      }
  LDS_BAR()

  // ===== Phase 3: N2 = P_lds x ctx[b]^T, K=256 (shared B) =====
#pragma unroll
  for (int r = 0; r < 2; ++r)
#pragma unroll
    for (int c = 0; c < 4; ++c) acc[r][c] = (f32x4){0.f, 0.f, 0.f, 0.f};
  cur = 0;
  {
    const int NSTEP = 8;
#pragma unroll 1
    for (int ks = 0; ks < NSTEP; ++ks) {
      short* Sc = &S[cur * BUFS];
      WAIT_ENTER3(4, 2)
      half8v fa[2], fb[4];
#pragma unroll
      for (int r = 0; r < 2; ++r) {
        int ck = ((ks * 4 + kh) ^ rmask[r]) << 3;
        fa[r] = *reinterpret_cast<const half8v*>(&P_lds[rowM[r] + ck]);
      }
#pragma unroll
      for (int c = 0; c < 4; ++c)
        fb[c] = *reinterpret_cast<const half8v*>(&Sc[offB2[c]]);
      __builtin_amdgcn_s_setprio(1);
#pragma unroll
      for (int r = 0; r < 2; ++r)
#pragma unroll
        for (int c = 0; c < 4; ++c)
          acc[r][c] = __builtin_amdgcn_mfma_f32_16x16x32_f16(fa[r], fb[c], acc[r][c], 0, 0, 0);
      __builtin_amdgcn_s_setprio(0);
      BAR_EXIT()
      if (ks + 3 < NSTEP)
        st_p23(Sc, gC, LL, wave, lane, (ks + 3) * 32);
      cur = (cur == 2) ? 0 : cur + 1;
    }
  }

  size_t nbase = (size_t)b * IDF * KHC + h * CDF;
#pragma unroll
  for (int r = 0; r < 2; ++r)
#pragma unroll
    for (int c = 0; c < 4; ++c)
#pragma unroll
      for (int reg = 0; reg < 4; ++reg) {
        int row = g * 32 + r * 16 + rowq + reg;
        int col = w4 * 64 + c * 16 + ln15;
        N216[nbase + (size_t)row * KHC + col] = f2h(acc[r][c][reg]);
      }
}

// ---------------------------------------------------------------------------
// K4 (MFMA fp16, 3-deep, b-paired) + P-transpose blocks.
// blocks 0..255: GEMM g(2 K-halves) x bp(16) x ot(8), 2 b-groups of 4 waves.
//   BOTH K-half groups atomicAdd into out (zeroed by k_prep; IEEE fadd is
//   commutative so the order-free atomic sum is bit-deterministic).
// blocks 256..383: attn_out transpose (depends only on P16; runs
//   concurrently with the GEMM blocks).
// ---------------------------------------------------------------------------
__device__ __forceinline__ void k4_stage(short* dst,
                                         const short* gA0, const short* gA1,
                                         const short* gW,
                                         int wave, int lane, int kk0, int obase) {
  int h4 = kk0 >> 8, cb = kk0 & 255;
#pragma unroll
  for (int j = 0; j < 2; ++j) {
    int inst = wave * 2 + j;               // 0..15
    if (inst < 8) {                        // A: 2 groups x 4 insts
      int gi = inst >> 2;
      int rb = (inst & 3) * 16;
      int r  = rb + (lane >> 2);           // 0..63
      int gc = (lane & 3) ^ ((r >> 1) & 3);
      const short* src = gi ? gA1 : gA0;
      GLDS16(src + (size_t)r * KHC + kk0 + gc * 8, dst + gi * 2048 + rb * 32);
    } else {                               // B: W rows, shared
      int bi = inst - 8;                   // 0..7
      int brow = bi * 16 + (lane >> 2);    // 0..127
      int gc = (lane & 3) ^ ((brow >> 1) & 3);
      GLDS16(gW + (size_t)(h4 * SSZ + obase + brow) * CDF + cb + gc * 8,
             dst + 4096 + bi * 512);
    }
  }
}

__global__ __launch_bounds__(512) void k4_mfma(const unsigned short* __restrict__ N216,
                                               const unsigned short* __restrict__ W16,
                                               const unsigned short* __restrict__ P16,
                                               float* __restrict__ out0,
                                               float* __restrict__ outa) {
  __shared__ __align__(16) short S[3 * 8192];   // 48 KB

  int blk = blockIdx.x;
  int t = threadIdx.x;

  if (blk >= 256) {
    // ---- P transpose: attn_out[b][l][i] = sum_h P16[bh][i][l], 512 thr ----
    int bblk = blk - 256;
    int b = bblk >> 2, lt = bblk & 3;
    int l0 = lt * 64;
    float* T = reinterpret_cast<float*>(S);    // [64][65] floats (16.6 KB)
    float4 acc2[2];
#pragma unroll
    for (int p = 0; p < 2; ++p) acc2[p] = make_float4(0.f, 0.f, 0.f, 0.f);
    for (int h = 0; h < NH; ++h) {
      size_t src = (size_t)(b * NH + h) * IDF * LL;
#pragma unroll
      for (int p = 0; p < 2; ++p) {
        int f = t + p * 512;
        int i = f >> 4, lc = (f & 15) * 4;
        ushort4 u = *reinterpret_cast<const ushort4*>(&P16[src + i * LL + l0 + lc]);
        acc2[p].x += h2f(u.x); acc2[p].y += h2f(u.y);
        acc2[p].z += h2f(u.z); acc2[p].w += h2f(u.w);
      }
    }
#pragma unroll
    for (int p = 0; p < 2; ++p) {
      int f = t + p * 512;
      int i = f >> 4, lc = (f & 15) * 4;
      T[i * 65 + lc + 0] = acc2[p].x; T[i * 65 + lc + 1] = acc2[p].y;
      T[i * 65 + lc + 2] = acc2[p].z; T[i * 65 + lc + 3] = acc2[p].w;
    }
    __syncthreads();
#pragma unroll
    for (int p = 0; p < 2; ++p) {
      int f = t + p * 512;
      int lr = f >> 4, ic = (f & 15) * 4;
      float4 v = {T[(ic + 0) * 65 + lr], T[(ic + 1) * 65 + lr],
                  T[(ic + 2) * 65 + lr], T[(ic + 3) * 65 + lr]};
      *reinterpret_cast<float4*>(&outa[((size_t)b * LL + l0 + lr) * IDF + ic]) = v;
    }
    return;
  }

  int g = blk >> 7;
  int r7 = blk & 127;
  int bp = r7 >> 3, ot = r7 & 7;
  int obase = ot * 128;
  int lane = t & 63, wave = t >> 6;             // 0..7
  int gr = wave >> 2, w4 = wave & 3;            // b-group, wave-in-group
  int ln15 = lane & 15, kh = lane >> 4;

  int b = bp * 2 + gr;
  const short* gA0 = (const short*)N216 + (size_t)(bp * 2 + 0) * IDF * KHC;
  const short* gA1 = (const short*)N216 + (size_t)(bp * 2 + 1) * IDF * KHC;
  const short* gW  = (const short*)W16;

  int offA[4], offB[2];
#pragma unroll
  for (int r = 0; r < 4; ++r) {
    int row = r * 16 + ln15;                   // 0..63
    offA[r] = gr * 2048 + row * 32 + ((kh ^ ((row >> 1) & 3)) * 8);
  }
#pragma unroll
  for (int c = 0; c < 2; ++c) {
    int row = w4 * 32 + c * 16 + ln15;         // 0..127
    offB[c] = 4096 + row * 32 + ((kh ^ ((row >> 1) & 3)) * 8);
  }

  int kbase = g * (KHC / 2);
  f32x4 acc[4][2] = {};

  k4_stage(&S[0],        gA0, gA1, gW, wave, lane, kbase, obase);
  k4_stage(&S[8192],     gA0, gA1, gW, wave, lane, kbase + 32, obase);
  k4_stage(&S[2 * 8192], gA0, gA1, gW, wave, lane, kbase + 64, obase);
  int cur = 0;

  const int NSTEP = 32;
#pragma unroll 1
  for (int ks = 0; ks < NSTEP; ++ks) {
    short* Sc = &S[cur * 8192];
    WAIT_ENTER3(4, 2)
    half8v fa[4], fb[2];
#pragma unroll
    for (int r = 0; r < 4; ++r)
      fa[r] = *reinterpret_cast<const half8v*>(&Sc[offA[r]]);
#pragma unroll
    for (int c = 0; c < 2; ++c)
      fb[c] = *reinterpret_cast<const half8v*>(&Sc[offB[c]]);
    __builtin_amdgcn_s_setprio(1);
#pragma unroll
    for (int r = 0; r < 4; ++r)
#pragma unroll
      for (int c = 0; c < 2; ++c)
        acc[r][c] = __builtin_amdgcn_mfma_f32_16x16x32_f16(fa[r], fb[c], acc[r][c], 0, 0, 0);
    __builtin_amdgcn_s_setprio(0);
    BAR_EXIT()
    if (ks + 3 < NSTEP)
      k4_stage(Sc, gA0, gA1, gW, wave, lane, kbase + (ks + 3) * 32, obase);
    cur = (cur == 2) ? 0 : cur + 1;
  }

  int rowq = (lane >> 4) * 4;
#pragma unroll
  for (int r = 0; r < 4; ++r)
#pragma unroll
    for (int c = 0; c < 2; ++c)
#pragma unroll
      for (int reg = 0; reg < 4; ++reg)
        atomicAdd(&out0[((size_t)b * IDF + r * 16 + rowq + reg) * SSZ +
                        obase + w4 * 32 + c * 16 + ln15], acc[r][c][reg]);
}

// ---------------------------------------------------------------------------
extern "C" void kernel_launch(void* const* d_in, const int* in_sizes, int n_in,
                              void* d_out, int out_size, void* d_ws, size_t ws_size,
                              hipStream_t stream) {
  const float* wc  = (const float*)d_in[0];   // [32][64][1024]
  const float* ctx = (const float*)d_in[1];   // [32][256][256]
  const float* W   = (const float*)d_in[2];   // [8][1024][256]
  float* out = (float*)d_out;

  const size_t NE = 2097152;   // elems of wc == W == ctx
  const size_t NM = 4194304;   // elems of P == N2
  unsigned short* p = (unsigned short*)d_ws;
  unsigned short *wc16 = p;   p += NE;
  unsigned short *Wt16 = p;   p += NE;
  unsigned short *W16  = p;   p += NE;
  unsigned short *ctx16 = p;  p += NE;
  unsigned short *cT16 = p;   p += NE;
  unsigned short *P16  = p;   p += NM;
  unsigned short *N216 = p;   p += NM;

  k_prep  <<<5120, 256, 0, stream>>>(wc, W, ctx, wc16, W16, ctx16, Wt16, cT16, out);
  k123    <<<256, 512, 0, stream>>>(wc16, Wt16, cT16, ctx16, P16, N216);
  k4_mfma <<<384, 512, 0, stream>>>(N216, W16, P16, out,
                                    out + (size_t)BB * IDF * SSZ);
}

// Round 24
// 75.398 us; speedup vs baseline: 1.0260x; 1.0260x over previous
//
#include <hip/hip_runtime.h>
#include <hip/hip_bf16.h>

#define BB 32
#define IDF 64
#define CDF 256
#define SSZ 1024
#define NH 8
#define LL 256
#define KHC 2048   // NH*CDF

typedef __attribute__((ext_vector_type(8))) _Float16 half8v;   // 8 fp16
typedef __attribute__((ext_vector_type(4))) float f32x4;       // MFMA acc

// async global->LDS, 16B per lane, LDS dest = wave-uniform base + lane*16
#define GLDS16(g, l) __builtin_amdgcn_global_load_lds(                        \
    (const __attribute__((address_space(1))) void*)(g),                       \
    (__attribute__((address_space(3))) void*)(l), 16, 0, 0)

// 3-deep pipeline phase entry (T3+T4): wait only for the CURRENT buffer's
// DMA, leaving the next TWO stages in flight. Never vmcnt(0) mid-loop.
#define WAIT_ENTER3(NFULL, NHALF)                                             \
  { if (ks < NSTEP - 2)                                                       \
      asm volatile("s_waitcnt vmcnt(" #NFULL ")" ::: "memory");               \
    else if (ks == NSTEP - 2)                                                 \
      asm volatile("s_waitcnt vmcnt(" #NHALF ")" ::: "memory");               \
    else                                                                      \
      asm volatile("s_waitcnt vmcnt(0)" ::: "memory");                        \
    __builtin_amdgcn_s_barrier();                                             \
    __builtin_amdgcn_sched_barrier(0); }
// phase-1 variant: PER-WAVE vmcnt constants (waves 0-3 issue 3 insts/stage,
// waves 4-7 issue 2) — removes the 4 dup-A instructions/step that existed
// only to keep vmcnt wave-uniform (17% of phase-1 DMA).
#define WAIT_P1()                                                             \
  { if (ks < NSTEP - 2) {                                                     \
      if (wave < 4) asm volatile("s_waitcnt vmcnt(6)" ::: "memory");          \
      else          asm volatile("s_waitcnt vmcnt(4)" ::: "memory");          \
    } else if (ks == NSTEP - 2) {                                             \
      if (wave < 4) asm volatile("s_waitcnt vmcnt(3)" ::: "memory");          \
      else          asm volatile("s_waitcnt vmcnt(2)" ::: "memory");          \
    } else asm volatile("s_waitcnt vmcnt(0)" ::: "memory");                   \
    __builtin_amdgcn_s_barrier();                                             \
    __builtin_amdgcn_sched_barrier(0); }
#define BAR_EXIT()                                                            \
  { __builtin_amdgcn_sched_barrier(0);                                        \
    __builtin_amdgcn_s_barrier();                                             \
    __builtin_amdgcn_sched_barrier(0); }
// LDS-only barrier: drains ds ops but leaves global_load_lds (vmcnt) in
// flight — lets phase-3 prefetch ride through the softmax.
#define LDS_BAR()                                                             \
  { asm volatile("s_waitcnt lgkmcnt(0)" ::: "memory");                        \
    __builtin_amdgcn_s_barrier();                                             \
    __builtin_amdgcn_sched_barrier(0); }

__device__ inline unsigned short f2h(float x) {
  _Float16 h = (_Float16)x;
  return *reinterpret_cast<unsigned short*>(&h);
}
__device__ inline float h2f(unsigned short u) {
  _Float16 h = *reinterpret_cast<_Float16*>(&u);
  return (float)h;
}

// ---------------------------------------------------------------------------
// Fused prep: blocks 0..6143 elementwise casts (wc,W,ctx -> fp16);
// blocks 6144..6655 -> Wt16 [h][c][o]; 6656..7167 -> cT16 [b][l][c].
// ---------------------------------------------------------------------------
__global__ __launch_bounds__(256) void k_prep(const float* __restrict__ wc,
                                              const float* __restrict__ W,
                                              const float* __restrict__ ctx,
                                              unsigned short* __restrict__ wc16,
                                              unsigned short* __restrict__ W16,
                                              unsigned short* __restrict__ ctx16,
                                              unsigned short* __restrict__ Wt16,
                                              unsigned short* __restrict__ cT16) {
  __shared__ float Tt[64][65];
  int blk0 = blockIdx.x;
  int t = threadIdx.x;
  if (blk0 < 6144) {                       // elementwise casts
    int sel = blk0 >> 11;
    int idx = ((blk0 & 2047) * 256 + t) * 4;
    const float* src = (sel == 0) ? wc : (sel == 1) ? W : ctx;
    unsigned short* d = (sel == 0) ? wc16 : (sel == 1) ? W16 : ctx16;
    float4 v = *reinterpret_cast<const float4*>(&src[idx]);
    __align__(8) unsigned short h[4] = {f2h(v.x), f2h(v.y), f2h(v.z), f2h(v.w)};
    *reinterpret_cast<int2*>(&d[idx]) = *reinterpret_cast<int2*>(h);
  } else if (blk0 < 6656) {                // W -> Wt16 [h][c][o]
    int blk = blk0 - 6144;
    int h = blk >> 6, ot = (blk >> 2) & 15, cq = blk & 3;
    int og = ot * 64, cg = cq * 64;
    int o_l = t >> 4, c4 = (t & 15) * 4;
#pragma unroll
    for (int p = 0; p < 4; ++p) {
      int o = o_l + 16 * p;
      float4 v = *reinterpret_cast<const float4*>(
          &W[((size_t)h * SSZ + og + o) * CDF + cg + c4]);
      Tt[c4 + 0][o] = v.x; Tt[c4 + 1][o] = v.y;
      Tt[c4 + 2][o] = v.z; Tt[c4 + 3][o] = v.w;
    }
    __syncthreads();
    int c_l = t >> 2;
#pragma unroll
    for (int p = 0; p < 4; ++p) {
      int o0 = ((t & 3) + 4 * p) * 4;
      __align__(8) unsigned short hv[4];
#pragma unroll
      for (int j = 0; j < 4; ++j) hv[j] = f2h(Tt[c_l][o0 + j]);
      size_t base = ((size_t)h * CDF + cg + c_l) * SSZ + og + o0;
      *reinterpret_cast<int2*>(&Wt16[base]) = *reinterpret_cast<int2*>(hv);
    }
  } else {                                 // ctx -> cT16 [b][l][c]
    int blk = blk0 - 6656;
    int b = blk >> 4, cq = (blk >> 2) & 3, lt = blk & 3;
    int cg = cq * 64, lg = lt * 64;
    int c_l = t >> 4, l4 = (t & 15) * 4;
#pragma unroll
    for (int p = 0; p < 4; ++p) {
      int c = c_l + 16 * p;
      float4 v = *reinterpret_cast<const float4*>(
          &ctx[((size_t)b * CDF + cg + c) * LL + lg + l4]);
      Tt[l4 + 0][c] = v.x; Tt[l4 + 1][c] = v.y;
      Tt[l4 + 2][c] = v.z; Tt[l4 + 3][c] = v.w;
    }
    __syncthreads();
    int l_l = t >> 2;
#pragma unroll
    for (int p = 0; p < 4; ++p) {
      int c0 = ((t & 3) + 4 * p) * 4;
      __align__(8) unsigned short hv[4];
#pragma unroll
      for (int j = 0; j < 4; ++j) hv[j] = f2h(Tt[l_l][c0 + j]);
      size_t base = ((size_t)b * LL + lg + l_l) * CDF + cg + c0;
      *reinterpret_cast<int2*>(&cT16[base]) = *reinterpret_cast<int2*>(hv);
    }
  }
}

// ---------------------------------------------------------------------------
// k123: fused K1+K2+K3, block = (b,h), 512 thr = 8 waves = 2 groups by
// row-half. Phase 1 stages Wt[h] once; phases 2/3 stage cT[b]/ctx[b] once.
// Phase-1 dup-A removed (per-wave vmcnt in WAIT_P1): 20 insts/step.
// LDS: 3 x 20KB staging + 32KB M/P_lds = 92 KB.
// ---------------------------------------------------------------------------
#define BUFS 10240   // shorts per staging buffer (20 KB): A [0,2048) B [2048,10240)

// phase-1 stage, 20 insts: waves 0-3 do {1 A, 2 B}; waves 4-7 do {2 B}.
__device__ __forceinline__ void st_p1(short* dst, const short* gA, const short* gB,
                                      int wave, int lane, int k0) {
  if (wave < 4) {                          // A rows 0..63
    int r = wave * 16 + (lane >> 2);
    int gc = (lane & 3) ^ ((r >> 1) & 3);
    GLDS16(gA + (size_t)r * SSZ + k0 + gc * 8, dst + wave * 512);
  }
#pragma unroll
  for (int j = 0; j < 2; ++j) {            // B rows 0..255
    int bi = wave * 2 + j;                 // 0..15
    int brow = bi * 16 + (lane >> 2);
    int gc = (lane & 3) ^ ((brow >> 1) & 3);
    GLDS16(gB + (size_t)brow * SSZ + k0 + gc * 8, dst + 2048 + bi * 512);
  }
}
// phase-2/3 stage, 16 insts (2/wave): shared B panel 256 rows @ [0,8192).
__device__ __forceinline__ void st_p23(short* dst, const short* gB, int ld,
                                       int wave, int lane, int k0) {
#pragma unroll
  for (int j = 0; j < 2; ++j) {
    int inst = wave * 2 + j;               // 0..15
    int brow = inst * 16 + (lane >> 2);    // 0..255
    int gc = (lane & 3) ^ ((brow >> 1) & 3);
    GLDS16(gB + (size_t)brow * ld + k0 + gc * 8, dst + inst * 512);
  }
}

__global__ __launch_bounds__(512) void k123(const unsigned short* __restrict__ wc16,
                                            const unsigned short* __restrict__ Wt16,
                                            const unsigned short* __restrict__ cT16,
                                            const unsigned short* __restrict__ ctx16,
                                            unsigned short* __restrict__ P16,
                                            unsigned short* __restrict__ N216) {
  __shared__ __align__(16) short S[3 * BUFS + 16384];   // 92 KB
  short* P_lds = &S[3 * BUFS];                           // 64 x 256 fp16

  int blk = blockIdx.x;                    // = bh
  int b = blk >> 3, h = blk & 7;
  int t = threadIdx.x;
  int lane = t & 63, wave = t >> 6;             // 0..7
  int g = wave >> 2, w4 = wave & 3;             // row-half group, wave-in-group
  int ln15 = lane & 15, kh = lane >> 4;
  int rowq = (lane >> 4) * 4;

  const short* gA = (const short*)wc16 + (size_t)b * IDF * SSZ;
  const short* gB = (const short*)Wt16 + (size_t)h * CDF * SSZ;
  const short* gT = (const short*)cT16 + (size_t)b * LL * CDF;
  const short* gC = (const short*)ctx16 + (size_t)b * CDF * LL;

  // A frag offsets: group g's rows = g*32 + r*16 + ln15 (global 0..63)
  int offA[2], rowM[2], rmask[2];
#pragma unroll
  for (int r = 0; r < 2; ++r) {
    int row = g * 32 + r * 16 + ln15;          // 0..63
    offA[r] = row * 32 + ((kh ^ ((row >> 1) & 3)) * 8);
    rowM[r] = row * 256;
    rmask[r] = row & 7;
  }
  // B frag offsets: phase 1 (Wt @2048) and phases 2/3 (shared panel @0)
  int offB1[4], offB2[4];
#pragma unroll
  for (int c = 0; c < 4; ++c) {
    int row = w4 * 64 + c * 16 + ln15;         // 0..255
    int swz = ((kh ^ ((row >> 1) & 3)) * 8);
    offB1[c] = 2048 + row * 32 + swz;
    offB2[c] = row * 32 + swz;
  }

  f32x4 acc[2][4] = {};

  // ===== Phase 1: M = wc x Wt^T, K=1024 =====
  st_p1(&S[0],        gA, gB, wave, lane, 0);
  st_p1(&S[BUFS],     gA, gB, wave, lane, 32);
  st_p1(&S[2 * BUFS], gA, gB, wave, lane, 64);
  int cur = 0;
  {
    const int NSTEP = 32;
#pragma unroll 1
    for (int ks = 0; ks < NSTEP; ++ks) {
      short* Sc = &S[cur * BUFS];
      WAIT_P1()
      half8v fa[2], fb[4];
#pragma unroll
      for (int r = 0; r < 2; ++r)
        fa[r] = *reinterpret_cast<const half8v*>(&Sc[offA[r]]);
#pragma unroll
      for (int c = 0; c < 4; ++c)
        fb[c] = *reinterpret_cast<const half8v*>(&Sc[offB1[c]]);
      __builtin_amdgcn_s_setprio(1);
#pragma unroll
      for (int r = 0; r < 2; ++r)
#pragma unroll
        for (int c = 0; c < 4; ++c)
          acc[r][c] = __builtin_amdgcn_mfma_f32_16x16x32_f16(fa[r], fb[c], acc[r][c], 0, 0, 0);
      __builtin_amdgcn_s_setprio(0);
      BAR_EXIT()
      if (ks + 3 < NSTEP)
        st_p1(Sc, gA, gB, wave, lane, (ks + 3) * 32);
      cur = (cur == 2) ? 0 : cur + 1;
    }
  }
  // M -> P_lds (fp16, chunk-XOR(row&7))
#pragma unroll
  for (int r = 0; r < 2; ++r)
#pragma unroll
    for (int c = 0; c < 4; ++c)
#pragma unroll
      for (int reg = 0; reg < 4; ++reg) {
        int row = g * 32 + r * 16 + rowq + reg;   // 0..63
        int col = w4 * 64 + c * 16 + ln15;        // 0..255
        P_lds[row * 256 + ((((col >> 3) ^ (row & 7)) << 3) + (col & 7))] =
            (short)f2h(acc[r][c][reg]);
      }
  LDS_BAR()

  // ===== Phase 2: logits = M_lds x cT[b]^T, K=256 (shared B) =====
#pragma unroll
  for (int r = 0; r < 2; ++r)
#pragma unroll
    for (int c = 0; c < 4; ++c) acc[r][c] = (f32x4){0.f, 0.f, 0.f, 0.f};
  st_p23(&S[0],        gT, CDF, wave, lane, 0);
  st_p23(&S[BUFS],     gT, CDF, wave, lane, 32);
  st_p23(&S[2 * BUFS], gT, CDF, wave, lane, 64);
  cur = 0;
  {
    const int NSTEP = 8;
#pragma unroll 1
    for (int ks = 0; ks < NSTEP; ++ks) {
      short* Sc = &S[cur * BUFS];
      WAIT_ENTER3(4, 2)
      half8v fa[2], fb[4];
#pragma unroll
      for (int r = 0; r < 2; ++r) {
        int ck = ((ks * 4 + kh) ^ rmask[r]) << 3;
        fa[r] = *reinterpret_cast<const half8v*>(&P_lds[rowM[r] + ck]);
      }
#pragma unroll
      for (int c = 0; c < 4; ++c)
        fb[c] = *reinterpret_cast<const half8v*>(&Sc[offB2[c]]);
      __builtin_amdgcn_s_setprio(1);
#pragma unroll
      for (int r = 0; r < 2; ++r)
#pragma unroll
        for (int c = 0; c < 4; ++c)
          acc[r][c] = __builtin_amdgcn_mfma_f32_16x16x32_f16(fa[r], fb[c], acc[r][c], 0, 0, 0);
      __builtin_amdgcn_s_setprio(0);
      BAR_EXIT()
      if (ks + 3 < NSTEP)
        st_p23(Sc, gT, CDF, wave, lane, (ks + 3) * 32);
      cur = (cur == 2) ? 0 : cur + 1;
    }
  }

  // Prefetch phase-3 B (ctx16) BEFORE softmax; stays in flight (LDS_BAR only).
  st_p23(&S[0],        gC, LL, wave, lane, 0);
  st_p23(&S[BUFS],     gC, LL, wave, lane, 32);
  st_p23(&S[2 * BUFS], gC, LL, wave, lane, 64);

  // ===== Softmax over l (cols). pm overlays first 1 KB of P_lds (M dead). =====
  float* pm = reinterpret_cast<float*>(P_lds);   // 64 rows x 4 floats
  float gmax[2][4], ginv[2][4];
#pragma unroll
  for (int r = 0; r < 2; ++r)
#pragma unroll
    for (int reg = 0; reg < 4; ++reg) {
      float m = fmaxf(fmaxf(acc[r][0][reg], acc[r][1][reg]),
                      fmaxf(acc[r][2][reg], acc[r][3][reg]));
#pragma unroll
      for (int msk = 8; msk >= 1; msk >>= 1) m = fmaxf(m, __shfl_xor(m, msk, 64));
      if (ln15 == 0) pm[(g * 32 + r * 16 + rowq + reg) * 4 + w4] = m;
    }
  LDS_BAR()
#pragma unroll
  for (int r = 0; r < 2; ++r)
#pragma unroll
    for (int reg = 0; reg < 4; ++reg) {
      int row = g * 32 + r * 16 + rowq + reg;
      float4 p0 = *reinterpret_cast<const float4*>(&pm[row * 4]);
      gmax[r][reg] = fmaxf(fmaxf(p0.x, p0.y), fmaxf(p0.z, p0.w));
    }
  LDS_BAR()
#pragma unroll
  for (int r = 0; r < 2; ++r)
#pragma unroll
    for (int reg = 0; reg < 4; ++reg) {
      float s = 0.f;
#pragma unroll
      for (int c = 0; c < 4; ++c) {
        acc[r][c][reg] = __expf(acc[r][c][reg] - gmax[r][reg]);
        s += acc[r][c][reg];
      }
#pragma unroll
      for (int msk = 8; msk >= 1; msk >>= 1) s += __shfl_xor(s, msk, 64);
      if (ln15 == 0) pm[(g * 32 + r * 16 + rowq + reg) * 4 + w4] = s;
    }
  LDS_BAR()
#pragma unroll
  for (int r = 0; r < 2; ++r)
#pragma unroll
    for (int reg = 0; reg < 4; ++reg) {
      int row = g * 32 + r * 16 + rowq + reg;
      float4 p0 = *reinterpret_cast<const float4*>(&pm[row * 4]);
      ginv[r][reg] = 1.f / (p0.x + p0.y + p0.z + p0.w);
    }
  LDS_BAR()   // pm fully consumed before P overwrites the region

  // P -> global (for transpose blocks) and -> P_lds (phase-3 A operand)
  size_t pbase = (size_t)blk * IDF * LL;
#pragma unroll
  for (int r = 0; r < 2; ++r)
#pragma unroll
    for (int c = 0; c < 4; ++c)
#pragma unroll
      for (int reg = 0; reg < 4; ++reg) {
        float p = acc[r][c][reg] * ginv[r][reg];
        int row = g * 32 + r * 16 + rowq + reg;
        int col = w4 * 64 + c * 16 + ln15;
        unsigned short ph = f2h(p);
        P16[pbase + (size_t)row * LL + col] = ph;
        P_lds[row * 256 + ((((col >> 3) ^ (row & 7)) << 3) + (col & 7))] = (short)ph;
      }
  LDS_BAR()

  // ===== Phase 3: N2 = P_lds x ctx[b]^T, K=256 (shared B) =====
#pragma unroll
  for (int r = 0; r < 2; ++r)
#pragma unroll
    for (int c = 0; c < 4; ++c) acc[r][c] = (f32x4){0.f, 0.f, 0.f, 0.f};
  cur = 0;
  {
    const int NSTEP = 8;
#pragma unroll 1
    for (int ks = 0; ks < NSTEP; ++ks) {
      short* Sc = &S[cur * BUFS];
      WAIT_ENTER3(4, 2)
      half8v fa[2], fb[4];
#pragma unroll
      for (int r = 0; r < 2; ++r) {
        int ck = ((ks * 4 + kh) ^ rmask[r]) << 3;
        fa[r] = *reinterpret_cast<const half8v*>(&P_lds[rowM[r] + ck]);
      }
#pragma unroll
      for (int c = 0; c < 4; ++c)
        fb[c] = *reinterpret_cast<const half8v*>(&Sc[offB2[c]]);
      __builtin_amdgcn_s_setprio(1);
#pragma unroll
      for (int r = 0; r < 2; ++r)
#pragma unroll
        for (int c = 0; c < 4; ++c)
          acc[r][c] = __builtin_amdgcn_mfma_f32_16x16x32_f16(fa[r], fb[c], acc[r][c], 0, 0, 0);
      __builtin_amdgcn_s_setprio(0);
      BAR_EXIT()
      if (ks + 3 < NSTEP)
        st_p23(Sc, gC, LL, wave, lane, (ks + 3) * 32);
      cur = (cur == 2) ? 0 : cur + 1;
    }
  }

  size_t nbase = (size_t)b * IDF * KHC + h * CDF;
#pragma unroll
  for (int r = 0; r < 2; ++r)
#pragma unroll
    for (int c = 0; c < 4; ++c)
#pragma unroll
      for (int reg = 0; reg < 4; ++reg) {
        int row = g * 32 + r * 16 + rowq + reg;
        int col = w4 * 64 + c * 16 + ln15;
        N216[nbase + (size_t)row * KHC + col] = f2h(acc[r][c][reg]);
      }
}

// ---------------------------------------------------------------------------
// K4 (MFMA fp16, 3-deep, b-paired) + P-transpose blocks.
// blocks 0..255: GEMM g(2 K-halves) x bp(16) x ot(8), 2 b-groups of 4 waves.
// blocks 256..383: attn_out transpose (depends only on P16 from k123 —
// runs CONCURRENTLY with the GEMM blocks).
// ---------------------------------------------------------------------------
__device__ __forceinline__ void k4_stage(short* dst,
                                         const short* gA0, const short* gA1,
                                         const short* gW,
                                         int wave, int lane, int kk0, int obase) {
  int h4 = kk0 >> 8, cb = kk0 & 255;
#pragma unroll
  for (int j = 0; j < 2; ++j) {
    int inst = wave * 2 + j;               // 0..15
    if (inst < 8) {                        // A: 2 groups x 4 insts
      int gi = inst >> 2;
      int rb = (inst & 3) * 16;
      int r  = rb + (lane >> 2);           // 0..63
      int gc = (lane & 3) ^ ((r >> 1) & 3);
      const short* src = gi ? gA1 : gA0;
      GLDS16(src + (size_t)r * KHC + kk0 + gc * 8, dst + gi * 2048 + rb * 32);
    } else {                               // B: W rows, shared
      int bi = inst - 8;                   // 0..7
      int brow = bi * 16 + (lane >> 2);    // 0..127
      int gc = (lane & 3) ^ ((brow >> 1) & 3);
      GLDS16(gW + (size_t)(h4 * SSZ + obase + brow) * CDF + cb + gc * 8,
             dst + 4096 + bi * 512);
    }
  }
}

__global__ __launch_bounds__(512) void k4_mfma(const unsigned short* __restrict__ N216,
                                               const unsigned short* __restrict__ W16,
                                               const unsigned short* __restrict__ P16,
                                               float* __restrict__ out0,
                                               float* __restrict__ out1,
                                               float* __restrict__ outa) {
  __shared__ __align__(16) short S[3 * 8192];   // 48 KB

  int blk = blockIdx.x;
  int t = threadIdx.x;

  if (blk >= 256) {
    // ---- P transpose: attn_out[b][l][i] = sum_h P16[bh][i][l], 512 thr ----
    int bblk = blk - 256;
    int b = bblk >> 2, lt = bblk & 3;
    int l0 = lt * 64;
    float* T = reinterpret_cast<float*>(S);    // [64][65] floats (16.6 KB)
    float4 acc2[2];
#pragma unroll
    for (int p = 0; p < 2; ++p) acc2[p] = make_float4(0.f, 0.f, 0.f, 0.f);
    for (int h = 0; h < NH; ++h) {
      size_t src = (size_t)(b * NH + h) * IDF * LL;
#pragma unroll
      for (int p = 0; p < 2; ++p) {
        int f = t + p * 512;
        int i = f >> 4, lc = (f & 15) * 4;
        ushort4 u = *reinterpret_cast<const ushort4*>(&P16[src + i * LL + l0 + lc]);
        acc2[p].x += h2f(u.x); acc2[p].y += h2f(u.y);
        acc2[p].z += h2f(u.z); acc2[p].w += h2f(u.w);
      }
    }
#pragma unroll
    for (int p = 0; p < 2; ++p) {
      int f = t + p * 512;
      int i = f >> 4, lc = (f & 15) * 4;
      T[i * 65 + lc + 0] = acc2[p].x; T[i * 65 + lc + 1] = acc2[p].y;
      T[i * 65 + lc + 2] = acc2[p].z; T[i * 65 + lc + 3] = acc2[p].w;
    }
    __syncthreads();
#pragma unroll
    for (int p = 0; p < 2; ++p) {
      int f = t + p * 512;
      int lr = f >> 4, ic = (f & 15) * 4;
      float4 v = {T[(ic + 0) * 65 + lr], T[(ic + 1) * 65 + lr],
                  T[(ic + 2) * 65 + lr], T[(ic + 3) * 65 + lr]};
      *reinterpret_cast<float4*>(&outa[((size_t)b * LL + l0 + lr) * IDF + ic]) = v;
    }
    return;
  }

  int g = blk >> 7;
  int r7 = blk & 127;
  int bp = r7 >> 3, ot = r7 & 7;
  int obase = ot * 128;
  int lane = t & 63, wave = t >> 6;             // 0..7
  int gr = wave >> 2, w4 = wave & 3;            // b-group, wave-in-group
  int ln15 = lane & 15, kh = lane >> 4;

  int b = bp * 2 + gr;
  const short* gA0 = (const short*)N216 + (size_t)(bp * 2 + 0) * IDF * KHC;
  const short* gA1 = (const short*)N216 + (size_t)(bp * 2 + 1) * IDF * KHC;
  const short* gW  = (const short*)W16;

  int offA[4], offB[2];
#pragma unroll
  for (int r = 0; r < 4; ++r) {
    int row = r * 16 + ln15;                   // 0..63
    offA[r] = gr * 2048 + row * 32 + ((kh ^ ((row >> 1) & 3)) * 8);
  }
#pragma unroll
  for (int c = 0; c < 2; ++c) {
    int row = w4 * 32 + c * 16 + ln15;         // 0..127
    offB[c] = 4096 + row * 32 + ((kh ^ ((row >> 1) & 3)) * 8);
  }

  int kbase = g * (KHC / 2);
  f32x4 acc[4][2] = {};

  k4_stage(&S[0],        gA0, gA1, gW, wave, lane, kbase, obase);
  k4_stage(&S[8192],     gA0, gA1, gW, wave, lane, kbase + 32, obase);
  k4_stage(&S[2 * 8192], gA0, gA1, gW, wave, lane, kbase + 64, obase);
  int cur = 0;

  const int NSTEP = 32;
#pragma unroll 1
  for (int ks = 0; ks < NSTEP; ++ks) {
    short* Sc = &S[cur * 8192];
    WAIT_ENTER3(4, 2)
    half8v fa[4], fb[2];
#pragma unroll
    for (int r = 0; r < 4; ++r)
      fa[r] = *reinterpret_cast<const half8v*>(&Sc[offA[r]]);
#pragma unroll
    for (int c = 0; c < 2; ++c)
      fb[c] = *reinterpret_cast<const half8v*>(&Sc[offB[c]]);
    __builtin_amdgcn_s_setprio(1);
#pragma unroll
    for (int r = 0; r < 4; ++r)
#pragma unroll
      for (int c = 0; c < 2; ++c)
        acc[r][c] = __builtin_amdgcn_mfma_f32_16x16x32_f16(fa[r], fb[c], acc[r][c], 0, 0, 0);
    __builtin_amdgcn_s_setprio(0);
    BAR_EXIT()
    if (ks + 3 < NSTEP)
      k4_stage(Sc, gA0, gA1, gW, wave, lane, kbase + (ks + 3) * 32, obase);
    cur = (cur == 2) ? 0 : cur + 1;
  }

  float* dst = (g == 0) ? out0 : out1;
  int rowq = (lane >> 4) * 4;
#pragma unroll
  for (int r = 0; r < 4; ++r)
#pragma unroll
    for (int c = 0; c < 2; ++c)
#pragma unroll
      for (int reg = 0; reg < 4; ++reg)
        dst[((size_t)b * IDF + r * 16 + rowq + reg) * SSZ +
            obase + w4 * 32 + c * 16 + ln15] = acc[r][c][reg];
}

// ---------------------------------------------------------------------------
// k_add: out[idx] += Pbuf[idx] (fold k4's g=1 K-half partial).
// ---------------------------------------------------------------------------
__global__ __launch_bounds__(256) void k_add(float* __restrict__ out,
                                             const float* __restrict__ Pbuf) {
  int idx = blockIdx.x * 256 + threadIdx.x;
  float4 a = reinterpret_cast<float4*>(out)[idx];
  float4 p = reinterpret_cast<const float4*>(Pbuf)[idx];
  a.x += p.x; a.y += p.y; a.z += p.z; a.w += p.w;
  reinterpret_cast<float4*>(out)[idx] = a;
}

// ---------------------------------------------------------------------------
extern "C" void kernel_launch(void* const* d_in, const int* in_sizes, int n_in,
                              void* d_out, int out_size, void* d_ws, size_t ws_size,
                              hipStream_t stream) {
  const float* wc  = (const float*)d_in[0];   // [32][64][1024]
  const float* ctx = (const float*)d_in[1];   // [32][256][256]
  const float* W   = (const float*)d_in[2];   // [8][1024][256]
  float* out = (float*)d_out;

  const size_t NE = 2097152;   // elems of wc == W == ctx
  const size_t NM = 4194304;   // elems of P == N2
  unsigned short* p = (unsigned short*)d_ws;
  unsigned short *wc16 = p;   p += NE;
  unsigned short *Wt16 = p;   p += NE;
  unsigned short *W16  = p;   p += NE;
  unsigned short *ctx16 = p;  p += NE;
  unsigned short *cT16 = p;   p += NE;
  unsigned short *P16  = p;   p += NM;
  unsigned short *N216 = p;   p += NM;
  float* Pbuf = (float*)p;    // 2.1M floats

  k_prep  <<<7168, 256, 0, stream>>>(wc, W, ctx, wc16, W16, ctx16, Wt16, cT16);
  k123    <<<256, 512, 0, stream>>>(wc16, Wt16, cT16, ctx16, P16, N216);
  k4_mfma <<<384, 512, 0, stream>>>(N216, W16, P16, out, Pbuf,
                                    out + (size_t)BB * IDF * SSZ);
  k_add   <<<2048, 256, 0, stream>>>(out, Pbuf);
}